// Round 2
// baseline (1619.546 us; speedup 1.0000x reference)
//
#include <hip/hip_runtime.h>

// ---------------- problem constants ----------------
#define T_TOKENS 8192
#define H_DIM    2048
#define I_DIM    4096
#define NE       8
#define NPAIR    16384                 // T_TOKENS * TOP_K
#define BM       128
#define BN       128
#define BK       32
#define PADP     (NPAIR + NE * BM)     // 17408 rows (each expert segment padded to BM)
#define RT_MAX   (PADP / BM)           // 136 max row tiles

// ---------------- workspace layout (bytes) ----------------
#define WS_X    0ull
#define WS_W    (WS_X + (size_t)T_TOKENS * H_DIM * 2)
#define WS_H    (WS_W + (size_t)NE * I_DIM * H_DIM * 2)
#define WS_TOK  (WS_H + (size_t)PADP * I_DIM * 2)
#define WS_PW   (WS_TOK + (size_t)PADP * 4)
#define WS_META (WS_PW + (size_t)PADP * 4)

typedef __attribute__((ext_vector_type(8))) short bf16x8;   // 8 bf16 = 4 VGPRs
typedef __attribute__((ext_vector_type(4))) float f32x4;    // MFMA C/D

__device__ __forceinline__ unsigned short f2bf(float f) {
  union { float f; unsigned u; } a; a.f = f;
  unsigned r = a.u + 0x7fffu + ((a.u >> 16) & 1u);   // RNE
  return (unsigned short)(r >> 16);
}

__device__ __forceinline__ void gload16(const void* g, void* l) {
  __builtin_amdgcn_global_load_lds(
      (const __attribute__((address_space(1))) unsigned int*)g,
      (__attribute__((address_space(3))) unsigned int*)l,
      16, 0, 0);
}

// ---------------- fp32 -> bf16 conversion (vectorized, grid-stride) ----------------
__global__ void cvt_f32_bf16(const float* __restrict__ in,
                             unsigned short* __restrict__ out, int n4) {
  int i = blockIdx.x * blockDim.x + threadIdx.x;
  int stride = gridDim.x * blockDim.x;
  for (; i < n4; i += stride) {
    float4 v = ((const float4*)in)[i];
    ushort4 o;
    o.x = f2bf(v.x); o.y = f2bf(v.y); o.z = f2bf(v.z); o.w = f2bf(v.w);
    ((ushort4*)out)[i] = o;
  }
}

// ---------------- routing: count / scan / scatter ----------------
__global__ void route_count(const int* __restrict__ idx, int* __restrict__ meta) {
  int i = blockIdx.x * blockDim.x + threadIdx.x;
  if (i < NPAIR) atomicAdd(&meta[idx[i]], 1);
}

__global__ void route_scan(int* __restrict__ meta) {
  if (threadIdx.x == 0 && blockIdx.x == 0) {
    int off = 0;
    for (int e = 0; e < NE; ++e) {
      meta[16 + e] = off;
      int c = meta[e];
      off += ((c + BM - 1) / BM) * BM;
    }
    meta[16 + NE] = off;   // total padded rows
  }
}

__global__ void route_scatter(const int* __restrict__ idx, const float* __restrict__ w,
                              int* __restrict__ meta, int* __restrict__ tok,
                              float* __restrict__ pw) {
  int i = blockIdx.x * blockDim.x + threadIdx.x;
  if (i < NPAIR) {
    int e = idx[i];
    int pos = meta[16 + e] + atomicAdd(&meta[8 + e], 1);
    tok[pos] = i >> 1;     // token id (TOP_K = 2)
    pw[pos]  = w[i];
  }
}

// bijective XCD swizzle (gridDim.x % 8 == 0 for both GEMM grids)
__device__ __forceinline__ int xcd_swz(int bid, int nwg) {
  int cpx = nwg >> 3;
  return (bid & 7) * cpx + (bid >> 3);
}

// ---------------- grouped GEMM1: h = relu2(x_gather @ up[e]^T), bf16 out ----------------
// 2-phase double-buffered LDS; per-buffer layout [kchunk(4)][128 rows][8 elems] (conflict-free).
__global__ __launch_bounds__(256) void gemm_up(
    const unsigned short* __restrict__ X, const unsigned short* __restrict__ W,
    unsigned short* __restrict__ Hb, const int* __restrict__ meta,
    const int* __restrict__ tok) {
  __shared__ unsigned short ldsA[2 * BM * BK];   // 16 KB
  __shared__ unsigned short ldsB[2 * BN * BK];   // 16 KB
  const int* pstart = meta + 16;
  const int NT = I_DIM / BN;                 // 32
  int swz = xcd_swz(blockIdx.x, RT_MAX * NT);
  int rt = swz / NT, nt = swz % NT;
  int row0 = rt * BM;
  if (row0 >= pstart[NE]) return;
  int e = 0;
  #pragma unroll
  for (int q = 1; q < NE; ++q) if (row0 >= pstart[q]) e = q;

  int tid = threadIdx.x;
  int wv = tid >> 6, lane = tid & 63;
  int rowIdx = tid & 127;                    // staged row within tile
  int hiB = tid >> 7;                        // 0/1: k-subchunk within issue

  int tokA = tok[row0 + rowIdx]; if (tokA < 0) tokA = 0;   // pad rows read row 0
  const unsigned short* ap = X + (size_t)tokA * H_DIM + hiB * 8;
  const unsigned short* bp = W + (size_t)e * I_DIM * H_DIM
                               + (size_t)(nt * BN + rowIdx) * H_DIM + hiB * 8;

  int wm = wv >> 1, wn = wv & 1;
  int arow0 = wm * 64 + (lane & 15);
  int brow0 = wn * 64 + (lane & 15);
  int hi = lane >> 4;

  f32x4 acc[4][4] = {};

  const int NKT = H_DIM / BK;                // 64
  // prologue: stage tile 0 into buf 0
  {
    char* la = (char*)ldsA + wv * 1024;
    char* lb = (char*)ldsB + wv * 1024;
    gload16(ap,      la);
    gload16(ap + 16, la + 4096);
    gload16(bp,      lb);
    gload16(bp + 16, lb + 4096);
  }
  __syncthreads();

  int buf = 0;
  for (int kt = 0; kt < NKT; ++kt) {
    if (kt + 1 < NKT) {                      // stage next tile into other buffer
      const unsigned short* a0 = ap + (kt + 1) * BK;
      const unsigned short* b0 = bp + (kt + 1) * BK;
      char* la = (char*)ldsA + (buf ^ 1) * 8192 + wv * 1024;
      char* lb = (char*)ldsB + (buf ^ 1) * 8192 + wv * 1024;
      gload16(a0,      la);
      gload16(a0 + 16, la + 4096);
      gload16(b0,      lb);
      gload16(b0 + 16, lb + 4096);
    }
    const unsigned short* sA = ldsA + buf * 4096;   // shorts
    const unsigned short* sB = ldsB + buf * 4096;
    bf16x8 af[4], bfr[4];
    #pragma unroll
    for (int f = 0; f < 4; ++f) {
      af[f]  = *(const bf16x8*)(sA + hi * 1024 + (arow0 + f * 16) * 8);
      bfr[f] = *(const bf16x8*)(sB + hi * 1024 + (brow0 + f * 16) * 8);
    }
    #pragma unroll
    for (int fm = 0; fm < 4; ++fm)
      #pragma unroll
      for (int fn = 0; fn < 4; ++fn)
        acc[fm][fn] = __builtin_amdgcn_mfma_f32_16x16x32_bf16(af[fm], bfr[fn], acc[fm][fn], 0, 0, 0);
    __syncthreads();                         // drains vmcnt (next buf staged) + lgkm
    buf ^= 1;
  }

  // epilogue: relu2 -> bf16 -> store
  int crow = wm * 64 + ((lane >> 4) << 2);
  int ccol = nt * BN + wn * 64 + (lane & 15);
  #pragma unroll
  for (int fm = 0; fm < 4; ++fm) {
    #pragma unroll
    for (int j = 0; j < 4; ++j) {
      int p = row0 + crow + fm * 16 + j;
      unsigned short* dst = Hb + (size_t)p * I_DIM + ccol;
      #pragma unroll
      for (int fn = 0; fn < 4; ++fn) {
        float v = acc[fm][fn][j];
        v = v > 0.f ? v * v : 0.f;
        dst[fn * 16] = f2bf(v);
      }
    }
  }
}

// ---------------- grouped GEMM2: out[tok] += w * (h @ down[e]^T) ----------------
__global__ __launch_bounds__(256) void gemm_down(
    const unsigned short* __restrict__ Hb, const unsigned short* __restrict__ W,
    float* __restrict__ out, const int* __restrict__ meta,
    const int* __restrict__ tok, const float* __restrict__ pw) {
  __shared__ unsigned short ldsA[2 * BM * BK];
  __shared__ unsigned short ldsB[2 * BN * BK];
  const int* pstart = meta + 16;
  const int NT = H_DIM / BN;                 // 16
  int swz = xcd_swz(blockIdx.x, RT_MAX * NT);
  int rt = swz / NT, nt = swz % NT;
  int row0 = rt * BM;
  if (row0 >= pstart[NE]) return;
  int e = 0;
  #pragma unroll
  for (int q = 1; q < NE; ++q) if (row0 >= pstart[q]) e = q;

  int tid = threadIdx.x;
  int wv = tid >> 6, lane = tid & 63;
  int rowIdx = tid & 127;
  int hiB = tid >> 7;

  const unsigned short* ap = Hb + (size_t)(row0 + rowIdx) * I_DIM + hiB * 8;
  const unsigned short* bp = W + (size_t)e * H_DIM * I_DIM
                               + (size_t)(nt * BN + rowIdx) * I_DIM + hiB * 8;

  int wm = wv >> 1, wn = wv & 1;
  int arow0 = wm * 64 + (lane & 15);
  int brow0 = wn * 64 + (lane & 15);
  int hi = lane >> 4;

  f32x4 acc[4][4] = {};

  const int NKT = I_DIM / BK;                // 128
  {
    char* la = (char*)ldsA + wv * 1024;
    char* lb = (char*)ldsB + wv * 1024;
    gload16(ap,      la);
    gload16(ap + 16, la + 4096);
    gload16(bp,      lb);
    gload16(bp + 16, lb + 4096);
  }
  __syncthreads();

  int buf = 0;
  for (int kt = 0; kt < NKT; ++kt) {
    if (kt + 1 < NKT) {
      const unsigned short* a0 = ap + (kt + 1) * BK;
      const unsigned short* b0 = bp + (kt + 1) * BK;
      char* la = (char*)ldsA + (buf ^ 1) * 8192 + wv * 1024;
      char* lb = (char*)ldsB + (buf ^ 1) * 8192 + wv * 1024;
      gload16(a0,      la);
      gload16(a0 + 16, la + 4096);
      gload16(b0,      lb);
      gload16(b0 + 16, lb + 4096);
    }
    const unsigned short* sA = ldsA + buf * 4096;
    const unsigned short* sB = ldsB + buf * 4096;
    bf16x8 af[4], bfr[4];
    #pragma unroll
    for (int f = 0; f < 4; ++f) {
      af[f]  = *(const bf16x8*)(sA + hi * 1024 + (arow0 + f * 16) * 8);
      bfr[f] = *(const bf16x8*)(sB + hi * 1024 + (brow0 + f * 16) * 8);
    }
    #pragma unroll
    for (int fm = 0; fm < 4; ++fm)
      #pragma unroll
      for (int fn = 0; fn < 4; ++fn)
        acc[fm][fn] = __builtin_amdgcn_mfma_f32_16x16x32_bf16(af[fm], bfr[fn], acc[fm][fn], 0, 0, 0);
    __syncthreads();
    buf ^= 1;
  }

  int crow = wm * 64 + ((lane >> 4) << 2);
  int ccol = nt * BN + wn * 64 + (lane & 15);
  #pragma unroll
  for (int fm = 0; fm < 4; ++fm) {
    #pragma unroll
    for (int j = 0; j < 4; ++j) {
      int p = row0 + crow + fm * 16 + j;
      int t = tok[p];
      if (t < 0) continue;                   // padding row
      float wgt = pw[p];
      float* dst = out + (size_t)t * H_DIM + ccol;
      #pragma unroll
      for (int fn = 0; fn < 4; ++fn)
        atomicAdd(dst + fn * 16, wgt * acc[fm][fn][j]);
    }
  }
}

// ---------------- launch ----------------
extern "C" void kernel_launch(void* const* d_in, const int* in_sizes, int n_in,
                              void* d_out, int out_size, void* d_ws, size_t ws_size,
                              hipStream_t stream) {
  const float* x   = (const float*)d_in[0];
  const int*   tki = (const int*)d_in[1];
  const float* tkw = (const float*)d_in[2];
  const float* up  = (const float*)d_in[3];
  const float* dn  = (const float*)d_in[4];
  float* out = (float*)d_out;
  char* ws = (char*)d_ws;

  unsigned short* xb  = (unsigned short*)(ws + WS_X);
  unsigned short* wb  = (unsigned short*)(ws + WS_W);
  unsigned short* hb  = (unsigned short*)(ws + WS_H);
  int*            tok = (int*)(ws + WS_TOK);
  float*          pw  = (float*)(ws + WS_PW);
  int*            meta= (int*)(ws + WS_META);

  hipMemsetAsync(d_out, 0, (size_t)out_size * sizeof(float), stream);
  hipMemsetAsync(meta, 0, 128, stream);
  hipMemsetAsync(tok, 0xFF, (size_t)PADP * 4, stream);    // -1 = padding

  cvt_f32_bf16<<<2048, 256, 0, stream>>>(x, xb, T_TOKENS * H_DIM / 4);
  cvt_f32_bf16<<<4096, 256, 0, stream>>>(up, wb, NE * I_DIM * H_DIM / 4);

  route_count  <<<NPAIR / 256, 256, 0, stream>>>(tki, meta);
  route_scan   <<<1, 64, 0, stream>>>(meta);
  route_scatter<<<NPAIR / 256, 256, 0, stream>>>(tki, tkw, meta, tok, pw);

  gemm_up<<<RT_MAX * (I_DIM / BN), 256, 0, stream>>>(xb, wb, hb, meta, tok);

  cvt_f32_bf16<<<4096, 256, 0, stream>>>(dn, wb, NE * H_DIM * I_DIM / 4);

  gemm_down<<<RT_MAX * (H_DIM / BN), 256, 0, stream>>>(hb, wb, out, meta, tok, pw);
}

// Round 3
// 1499.813 us; speedup vs baseline: 1.0798x; 1.0798x over previous
//
#include <hip/hip_runtime.h>

// ---------------- problem constants ----------------
#define T_TOKENS 8192
#define H_DIM    2048
#define I_DIM    4096
#define NE       8
#define NPAIR    16384                  // T_TOKENS * TOP_K
#define PADBM    256                    // expert segment padding (= BM of GEMM tiles)
#define PADP     (NPAIR + NE * PADBM)   // 18432 worst-case padded rows
#define RT_MAX   (PADP / PADBM)         // 72 max row tiles

// 256x256x64 8-phase GEMM geometry
#define BM2 256
#define BN2 256
#define BK2 64
#define NTHR 512

// ---------------- workspace layout (bytes) ----------------
// x_bf16 33.5MB | w_bf16 134.2MB (shared up->down) | h_bf16 151.0MB | tok/pw/meta
#define WS_X    0ull
#define WS_W    (WS_X + (size_t)T_TOKENS * H_DIM * 2)
#define WS_H    (WS_W + (size_t)NE * I_DIM * H_DIM * 2)
#define WS_TOK  (WS_H + (size_t)PADP * I_DIM * 2)
#define WS_PW   (WS_TOK + (size_t)PADP * 4)
#define WS_META (WS_PW + (size_t)PADP * 4)

typedef __attribute__((ext_vector_type(8))) short bf16x8;   // 8 bf16 = 4 VGPRs
typedef __attribute__((ext_vector_type(4))) float f32x4;    // MFMA C/D

__device__ __forceinline__ unsigned short f2bf(float f) {
  union { float f; unsigned u; } a; a.f = f;
  unsigned r = a.u + 0x7fffu + ((a.u >> 16) & 1u);   // RNE
  return (unsigned short)(r >> 16);
}

__device__ __forceinline__ void gload16(const void* g, void* l) {
  __builtin_amdgcn_global_load_lds(
      (const __attribute__((address_space(1))) unsigned int*)g,
      (__attribute__((address_space(3))) unsigned int*)l,
      16, 0, 0);
}

// ---------------- fp32 -> bf16 conversion ----------------
__global__ void cvt_f32_bf16(const float* __restrict__ in,
                             unsigned short* __restrict__ out, int n4) {
  int i = blockIdx.x * blockDim.x + threadIdx.x;
  int stride = gridDim.x * blockDim.x;
  for (; i < n4; i += stride) {
    float4 v = ((const float4*)in)[i];
    ushort4 o;
    o.x = f2bf(v.x); o.y = f2bf(v.y); o.z = f2bf(v.z); o.w = f2bf(v.w);
    ((ushort4*)out)[i] = o;
  }
}

// ---------------- routing ----------------
__global__ void route_count(const int* __restrict__ idx, int* __restrict__ meta) {
  int i = blockIdx.x * blockDim.x + threadIdx.x;
  if (i < NPAIR) atomicAdd(&meta[idx[i]], 1);
}

__global__ void route_scan(int* __restrict__ meta) {
  if (threadIdx.x == 0 && blockIdx.x == 0) {
    int off = 0;
    for (int e = 0; e < NE; ++e) {
      meta[16 + e] = off;
      int c = meta[e];
      off += ((c + PADBM - 1) / PADBM) * PADBM;
    }
    meta[16 + NE] = off;
  }
}

__global__ void route_scatter(const int* __restrict__ idx, const float* __restrict__ w,
                              int* __restrict__ meta, int* __restrict__ tok,
                              float* __restrict__ pw) {
  int i = blockIdx.x * blockDim.x + threadIdx.x;
  if (i < NPAIR) {
    int e = idx[i];
    int pos = meta[16 + e] + atomicAdd(&meta[8 + e], 1);
    tok[pos] = i >> 1;
    pw[pos]  = w[i];
  }
}

// ---------------- 8-phase 256^2 grouped-GEMM core ----------------
// LDS: A dbuf [2][8 kc][256 rows][16B] = 64KB at 0; B same at 65536. Total 128KB.
// Phase (ks,fh): ds_read A frags fm=fh*4..+4 (and B frags if fh==0) of kstep ks
// from current buf; stage half-tiles of next tile; counted vmcnt; barrier;
// lgkm(0); setprio(1); 16 MFMA; setprio(0); barrier.
// Stage plan per window: c0 stages {A,B}-half0(t+1) (4 loads), c1 stages half1 (4).
// vmcnt(8) at c1 (ensures half1(t) for c2), vmcnt(4) at c3 (ensures half0(t+1) for c0').

#define STAGE_HALF(HK, KT, BS) do {                                            \
    int ko_ = (KT) * 64 + (HK) * 32 + sub * 16;        /* shorts */            \
    char* lA_ = smem + (BS) * 32768 + ((HK) * 4 + sub * 2) * 4096 + r16;       \
    char* lB_ = smem + 65536 + (BS) * 32768 + ((HK) * 4 + sub * 2) * 4096 + r16;\
    gload16(apt + ko_,     lA_);                                               \
    gload16(apt + ko_ + 8, lA_ + 4096);                                        \
    gload16(bpt + ko_,     lB_);                                               \
    gload16(bpt + ko_ + 8, lB_ + 4096);                                        \
  } while (0)

#define PHASE(KS, FH, DO_STAGE, DO_VM) do {                                    \
    bf16x8 af[4];                                                              \
    const char* aB_ = smem + bufc * 32768 + ((KS) * 4 + hi) * 4096;            \
    _Pragma("unroll")                                                          \
    for (int f = 0; f < 4; ++f)                                                \
      af[f] = *(const bf16x8*)(aB_ + arow_b + ((FH) * 4 + f) * 256);           \
    if ((FH) == 0) {                                                           \
      const char* bB_ = smem + 65536 + bufc * 32768 + ((KS) * 4 + hi) * 4096;  \
      _Pragma("unroll")                                                        \
      for (int f = 0; f < 4; ++f)                                              \
        bfr[f] = *(const bf16x8*)(bB_ + brow_b + f * 256);                     \
    }                                                                          \
    DO_STAGE;                                                                  \
    DO_VM;                                                                     \
    __builtin_amdgcn_s_barrier();                                              \
    asm volatile("s_waitcnt lgkmcnt(0)" ::: "memory");                         \
    __builtin_amdgcn_s_setprio(1);                                             \
    _Pragma("unroll")                                                          \
    for (int fm = 0; fm < 4; ++fm)                                             \
      _Pragma("unroll")                                                        \
      for (int fn = 0; fn < 4; ++fn)                                           \
        acc[(FH) * 4 + fm][fn] = __builtin_amdgcn_mfma_f32_16x16x32_bf16(      \
            af[fm], bfr[fn], acc[(FH) * 4 + fm][fn], 0, 0, 0);                 \
    __builtin_amdgcn_s_setprio(0);                                             \
    __builtin_amdgcn_s_barrier();                                              \
  } while (0)

#define GEMM_PROLOGUE()                                                        \
  STAGE_HALF(0, 0, 0);                                                         \
  STAGE_HALF(1, 0, 0);                                                         \
  asm volatile("s_waitcnt vmcnt(4)" ::: "memory");                             \
  __builtin_amdgcn_s_barrier();

#define GEMM_MAIN(NKT)                                                         \
  int bufc = 0;                                                                \
  for (int kt = 0; kt < (NKT); ++kt) {                                         \
    int ktn = (kt + 1 < (NKT)) ? kt + 1 : (NKT) - 1;  /* clamp: uniform vmcnt */\
    int bn_ = bufc ^ 1;                                                        \
    PHASE(0, 0, STAGE_HALF(0, ktn, bn_), (void)0);                             \
    PHASE(0, 1, STAGE_HALF(1, ktn, bn_),                                       \
          asm volatile("s_waitcnt vmcnt(8)" ::: "memory"));                    \
    PHASE(1, 0, (void)0, (void)0);                                             \
    PHASE(1, 1, (void)0,                                                       \
          asm volatile("s_waitcnt vmcnt(4)" ::: "memory"));                    \
    bufc ^= 1;                                                                 \
  }

// ---------------- GEMM1: h = relu2(x_gather @ up[e]^T) ----------------
__global__ __launch_bounds__(NTHR, 2) void gemm_up8(
    const unsigned short* __restrict__ X, const unsigned short* __restrict__ W,
    unsigned short* __restrict__ Hb, const int* __restrict__ meta,
    const int* __restrict__ tok) {
  extern __shared__ char smem[];
  const int* pstart = meta + 16;
  const int NTn = I_DIM / BN2;               // 16
  int rt = blockIdx.x / NTn, nt = blockIdx.x % NTn;
  int row0 = rt * BM2;
  if (row0 >= pstart[NE]) return;
  int e = 0;
  #pragma unroll
  for (int q = 1; q < NE; ++q) if (row0 >= pstart[q]) e = q;

  int tid = threadIdx.x;
  int wv = tid >> 6, lane = tid & 63;
  int r = tid & 255, sub = tid >> 8;         // stage row / kc-subgroup
  int r16 = r * 16;

  int tokA = tok[row0 + r]; if (tokA < 0) tokA = 0;
  const unsigned short* apt = X + (size_t)tokA * H_DIM;
  const unsigned short* bpt = W + (size_t)e * I_DIM * H_DIM
                                + (size_t)(nt * BN2 + r) * H_DIM;

  int wm = wv >> 2, wn = wv & 3;
  int hi = lane >> 4;
  int arow_b = (wm * 128 + (lane & 15)) * 16;   // byte offset of frag row base
  int brow_b = (wn * 64 + (lane & 15)) * 16;

  f32x4 acc[8][4] = {};
  bf16x8 bfr[4];

  GEMM_PROLOGUE();
  GEMM_MAIN(H_DIM / BK2);                    // 32 K-tiles

  // epilogue: relu2 -> bf16
  int crow0 = row0 + wm * 128 + (lane >> 4) * 4;
  int ccol0 = nt * BN2 + wn * 64 + (lane & 15);
  #pragma unroll
  for (int fm = 0; fm < 8; ++fm) {
    #pragma unroll
    for (int j = 0; j < 4; ++j) {
      int p = crow0 + fm * 16 + j;
      unsigned short* dst = Hb + (size_t)p * I_DIM + ccol0;
      #pragma unroll
      for (int fn = 0; fn < 4; ++fn) {
        float v = acc[fm][fn][j];
        v = v > 0.f ? v * v : 0.f;
        dst[fn * 16] = f2bf(v);
      }
    }
  }
}

// ---------------- GEMM2: out[tok] += w * (h @ down[e]^T) ----------------
__global__ __launch_bounds__(NTHR, 2) void gemm_down8(
    const unsigned short* __restrict__ Hb, const unsigned short* __restrict__ W,
    float* __restrict__ out, const int* __restrict__ meta,
    const int* __restrict__ tok, const float* __restrict__ pw) {
  extern __shared__ char smem[];
  const int* pstart = meta + 16;
  const int NTn = H_DIM / BN2;               // 8
  int rt = blockIdx.x / NTn, nt = blockIdx.x % NTn;
  int row0 = rt * BM2;
  if (row0 >= pstart[NE]) return;
  int e = 0;
  #pragma unroll
  for (int q = 1; q < NE; ++q) if (row0 >= pstart[q]) e = q;

  int tid = threadIdx.x;
  int wv = tid >> 6, lane = tid & 63;
  int r = tid & 255, sub = tid >> 8;
  int r16 = r * 16;

  const unsigned short* apt = Hb + (size_t)(row0 + r) * I_DIM;
  const unsigned short* bpt = W + (size_t)e * H_DIM * I_DIM
                                + (size_t)(nt * BN2 + r) * I_DIM;

  int wm = wv >> 2, wn = wv & 3;
  int hi = lane >> 4;
  int arow_b = (wm * 128 + (lane & 15)) * 16;
  int brow_b = (wn * 64 + (lane & 15)) * 16;

  f32x4 acc[8][4] = {};
  bf16x8 bfr[4];

  GEMM_PROLOGUE();
  GEMM_MAIN(I_DIM / BK2);                    // 64 K-tiles

  int crow0 = row0 + wm * 128 + (lane >> 4) * 4;
  int ccol0 = nt * BN2 + wn * 64 + (lane & 15);
  #pragma unroll
  for (int fm = 0; fm < 8; ++fm) {
    #pragma unroll
    for (int j = 0; j < 4; ++j) {
      int p = crow0 + fm * 16 + j;
      int t = tok[p];
      if (t < 0) continue;                   // padding row
      float wgt = pw[p];
      float* dst = out + (size_t)t * H_DIM + ccol0;
      #pragma unroll
      for (int fn = 0; fn < 4; ++fn)
        atomicAdd(dst + fn * 16, wgt * acc[fm][fn][j]);
    }
  }
}

// ---------------- launch ----------------
extern "C" void kernel_launch(void* const* d_in, const int* in_sizes, int n_in,
                              void* d_out, int out_size, void* d_ws, size_t ws_size,
                              hipStream_t stream) {
  const float* x   = (const float*)d_in[0];
  const int*   tki = (const int*)d_in[1];
  const float* tkw = (const float*)d_in[2];
  const float* up  = (const float*)d_in[3];
  const float* dn  = (const float*)d_in[4];
  float* out = (float*)d_out;
  char* ws = (char*)d_ws;

  unsigned short* xb  = (unsigned short*)(ws + WS_X);
  unsigned short* wb  = (unsigned short*)(ws + WS_W);
  unsigned short* hb  = (unsigned short*)(ws + WS_H);
  int*            tok = (int*)(ws + WS_TOK);
  float*          pw  = (float*)(ws + WS_PW);
  int*            meta= (int*)(ws + WS_META);

  // opt in to 128KB dynamic LDS (idempotent, host-side, capture-safe)
  hipFuncSetAttribute((const void*)gemm_up8,
                      hipFuncAttributeMaxDynamicSharedMemorySize, 131072);
  hipFuncSetAttribute((const void*)gemm_down8,
                      hipFuncAttributeMaxDynamicSharedMemorySize, 131072);

  hipMemsetAsync(d_out, 0, (size_t)out_size * sizeof(float), stream);
  hipMemsetAsync(meta, 0, 128, stream);
  hipMemsetAsync(tok, 0xFF, (size_t)PADP * 4, stream);    // -1 = padding

  cvt_f32_bf16<<<2048, 256, 0, stream>>>(x, xb, T_TOKENS * H_DIM / 4);
  cvt_f32_bf16<<<4096, 256, 0, stream>>>(up, wb, NE * I_DIM * H_DIM / 4);

  route_count  <<<NPAIR / 256, 256, 0, stream>>>(tki, meta);
  route_scan   <<<1, 64, 0, stream>>>(meta);
  route_scatter<<<NPAIR / 256, 256, 0, stream>>>(tki, tkw, meta, tok, pw);

  gemm_up8<<<RT_MAX * (I_DIM / BN2), NTHR, 131072, stream>>>(xb, wb, hb, meta, tok);

  cvt_f32_bf16<<<4096, 256, 0, stream>>>(dn, wb, NE * H_DIM * I_DIM / 4);

  gemm_down8<<<RT_MAX * (H_DIM / BN2), NTHR, 131072, stream>>>(hb, wb, out, meta, tok, pw);
}